// Round 6
// baseline (10633.674 us; speedup 1.0000x reference)
//
#include <hip/hip_runtime.h>
#include <stdint.h>

#define TT 128

typedef __attribute__((ext_vector_type(8))) short short8;
typedef __attribute__((ext_vector_type(4))) float f32x4;
typedef __attribute__((ext_vector_type(4))) uint32_t u32x4;

__device__ __forceinline__ float blo(uint32_t u){ union{uint32_t i; float f;} v; v.i = u << 16; return v.f; }
__device__ __forceinline__ float bhi(uint32_t u){ union{uint32_t i; float f;} v; v.i = u & 0xffff0000u; return v.f; }
__device__ __forceinline__ float bf2f(uint16_t u){ union{uint32_t i; float f;} v; v.i = ((uint32_t)u) << 16; return v.f; }
__device__ __forceinline__ uint16_t f2bf(float f){
  union{float f; uint32_t i;} v; v.f = f;
  uint32_t r = v.i + 0x7fffu + ((v.i >> 16) & 1u);
  return (uint16_t)(r >> 16);
}
__device__ __forceinline__ uint32_t bfpack(float a, float b) {
  return (uint32_t)f2bf(a) | ((uint32_t)f2bf(b) << 16);
}

// ---------------- prep kernels (unchanged from R5) ----------------
__global__ __launch_bounds__(256) void k_prep_mem(const float* __restrict__ mem,
                                                  uint32_t* __restrict__ memK,
                                                  uint32_t* __restrict__ memT) {
  int idx = blockIdx.x * 256 + threadIdx.x;   // 2 * 32*256*256
  if (idx < 2097152) {
    int e2 = idx & 255, k = (idx >> 8) & 255, b = idx >> 16;
    const float* p = mem + ((size_t)(b * 256 + k)) * 512 + e2 * 2;
    memK[idx] = bfpack(p[0], p[1]);
  } else {
    int j = idx - 2097152;
    int k = j & 255, e2 = (j >> 8) & 255, b = j >> 16;
    const float* p = mem + ((size_t)(b * 256 + k)) * 512 + e2 * 2;
    memT[j] = bfpack(p[0], p[1]);
  }
}

// Slice-tiled gate weights: Wsl[s][kc][t][kk], row j = (t&3)*512 + s*64 + (t>>2), k0 = kc*8+kk*2.
__global__ __launch_bounds__(256) void k_prep_wsl(const float* __restrict__ W_ih, const float* __restrict__ W_hh,
                                                  uint32_t* __restrict__ Wsl) {
  int idx = blockIdx.x * 256 + threadIdx.x;   // 1048576
  int kk = idx & 3, t = (idx >> 2) & 255, kc = (idx >> 10) & 127, s = idx >> 17;
  int j = (t & 3) * 512 + s * 64 + (t >> 2);
  int k0 = kc * 8 + kk * 2;
  float w0 = (k0 < 512) ? W_ih[(size_t)j * 1024 + k0] : W_hh[(size_t)j * 512 + (k0 - 512)];
  float w1 = (k0 + 1 < 512) ? W_ih[(size_t)j * 1024 + k0 + 1] : W_hh[(size_t)j * 512 + (k0 + 1 - 512)];
  Wsl[idx] = bfpack(w0, w1);
}

__global__ __launch_bounds__(256) void k_prep_wx(const float* __restrict__ W_ih,
                                                 const float* __restrict__ b_ih, const float* __restrict__ b_hh,
                                                 uint16_t* __restrict__ Wxp, float* __restrict__ biasp) {
  int idx = blockIdx.x * 256 + threadIdx.x;   // 2048*512
  int k = idx & 511, j = idx >> 9;
  Wxp[idx] = f2bf(W_ih[(size_t)j * 1024 + 512 + k]);
  if (k == 0) biasp[j] = b_ih[j] + b_hh[j];
}

__global__ __launch_bounds__(256) void k_prep_wo(const float* __restrict__ W_out, uint16_t* __restrict__ WoP) {
  int idx = blockIdx.x * 256 + threadIdx.x;   // 10112*512 (pad rows zeroed)
  if (idx < 5120000) WoP[idx] = f2bf(W_out[idx]);
  else WoP[idx] = 0;
}

__global__ __launch_bounds__(256) void k_gather_x(const float* __restrict__ emb, const int* __restrict__ tgt,
                                                  uint16_t* __restrict__ Axg) {
  int idx = blockIdx.x * 256 + threadIdx.x;   // 4096*512
  int k = idx & 511, m = idx >> 9;
  Axg[idx] = f2bf(emb[(size_t)tgt[m] * 512 + k]);
}

// ---------------- bf16 MFMA GEMM (unchanged from R5) ----------------
template<int MODE>
__global__ __launch_bounds__(256) void gemm_bt(const uint16_t* __restrict__ A, const uint16_t* __restrict__ B,
                                               const float* __restrict__ bias, void* __restrict__ Cout,
                                               int K, int Nreal, int ldc, int tilesN) {
  __shared__ __align__(16) uint16_t As[128 * 32];
  __shared__ __align__(16) uint16_t Bs[128 * 32];
  const int tid = threadIdx.x;
  const int wv = tid >> 6, lane = tid & 63;
  const int tm = blockIdx.x / tilesN, tn = blockIdx.x % tilesN;
  const int wr = wv >> 1, wc = wv & 1;

  f32x4 acc[4][4];
#pragma unroll
  for (int m = 0; m < 4; ++m)
#pragma unroll
    for (int n = 0; n < 4; ++n) acc[m][n] = (f32x4){0.f, 0.f, 0.f, 0.f};

  const int frow = lane & 15;
  const int fk = (lane >> 4) << 3;
  const int srow = lane >> 2;
  const int skof = (lane & 3) << 3;

  const uint16_t* Abase = A + (size_t)tm * 128 * K;
  const uint16_t* Bbase = B + (size_t)tn * 128 * K;

  for (int k0 = 0; k0 < K; k0 += 32) {
    __syncthreads();
#pragma unroll
    for (int i = 0; i < 2; ++i) {               // 8 chunks of 16 rows = 128 rows
      const int chunk = wv * 2 + i;
      const int row = chunk * 16 + srow;
      const uint16_t* ga = Abase + (size_t)row * K + k0 + skof;
      const uint16_t* gb = Bbase + (size_t)row * K + k0 + skof;
      __builtin_amdgcn_global_load_lds((const __attribute__((address_space(1))) uint32_t*)(const void*)ga,
                                       (__attribute__((address_space(3))) uint32_t*)(void*)(As + chunk * 512),
                                       16, 0, 0);
      __builtin_amdgcn_global_load_lds((const __attribute__((address_space(1))) uint32_t*)(const void*)gb,
                                       (__attribute__((address_space(3))) uint32_t*)(void*)(Bs + chunk * 512),
                                       16, 0, 0);
    }
    __syncthreads();
    short8 af[4], bfr[4];
#pragma unroll
    for (int m = 0; m < 4; ++m) af[m] = *(const short8*)(As + (wr * 64 + m * 16 + frow) * 32 + fk);
#pragma unroll
    for (int n = 0; n < 4; ++n) bfr[n] = *(const short8*)(Bs + (wc * 64 + n * 16 + frow) * 32 + fk);
#pragma unroll
    for (int m = 0; m < 4; ++m)
#pragma unroll
      for (int n = 0; n < 4; ++n)
        acc[m][n] = __builtin_amdgcn_mfma_f32_16x16x32_bf16(af[m], bfr[n], acc[m][n], 0, 0, 0);
  }

  const int crow = (lane >> 4) << 2;
  const int ccol = lane & 15;
#pragma unroll
  for (int n = 0; n < 4; ++n) {
    const int gcol = tn * 128 + wc * 64 + n * 16 + ccol;
    if (gcol < Nreal) {
      const float bv = bias[gcol];
#pragma unroll
      for (int m = 0; m < 4; ++m) {
#pragma unroll
        for (int j = 0; j < 4; ++j) {
          const int grow = tm * 128 + wr * 64 + m * 16 + crow + j;
          const float v = acc[m][n][j] + bv;
          if (MODE == 0) ((float*)Cout)[(size_t)grow * ldc + gcol] = v;
          else {
            int q = gcol >> 9, r = gcol & 511;
            int pos = ((r >> 6) << 8) + ((r & 63) << 2) + q;
            ((uint16_t*)Cout)[(size_t)grow * ldc + pos] = f2bf(v);
          }
        }
      }
    }
  }
}

// ---------------- per-batch 8-WG barrier ----------------
__device__ __forceinline__ void gbar(int* cnt, int target) {
  __syncthreads();
  if (threadIdx.x == 0) {
    __threadfence();
    __hip_atomic_fetch_add(cnt, 1, __ATOMIC_RELAXED, __HIP_MEMORY_SCOPE_AGENT);
    while (__hip_atomic_load(cnt, __ATOMIC_RELAXED, __HIP_MEMORY_SCOPE_AGENT) < target)
      __builtin_amdgcn_s_sleep(2);
  }
  __syncthreads();
  __threadfence();
}

// ---------------- recurrence: 256 WGs, g = b*8 + s (XCD = slice), split A/C/D ----------------
__global__ __launch_bounds__(256, 1) void recur_kernel(
    const uint32_t* __restrict__ memK, const uint32_t* __restrict__ memT,
    const uint32_t* __restrict__ Wsl, const uint16_t* __restrict__ Xgp,
    float* __restrict__ sgl, uint32_t* __restrict__ ctxg,
    uint16_t* __restrict__ hgl, uint16_t* __restrict__ hA, int* __restrict__ bar) {
  __shared__ __align__(16) uint32_t hx[512];       // [0..256)=ctx pairs, [256..512)=h pairs
  __shared__ float s_lds[256];                     // attention weights
  __shared__ float red[384];                       // reduce scratch: [0..128) scores, [128..256) cx, [256..384) cy
  __shared__ float r_lds[8];

  const int g = blockIdx.x;
  const int b = g >> 3, s = g & 7;                 // XCD = g%8 = s (round-robin heuristic)
  const int tid = threadIdx.x;
  const int lane = tid & 63, wv = tid >> 6;
  const int sub = tid & 31, p = tid >> 5;          // 32-lane group id / octile

  const uint32_t* mTb = memT + ((size_t)b << 16);  // [e2][k]
  const uint32_t* mKb = memK + ((size_t)b << 16);  // [k][e2]
  const uint32_t* wp = Wsl + ((size_t)s << 17) + tid * 4;
  int* cnt = bar + b * 32;

  float c = 0.f;
  hx[tid] = 0u; hx[256 + tid] = 0u;
  __syncthreads();

  for (int t = 0; t < TT; ++t) {
    const int base = 24 * t;
    // ---- A: partial scores for keys k = 32s + sub, e2-range p+8i ----
    {
      float sc = 0.f;
      const uint32_t* mp = mTb + ((size_t)p << 8) + 32 * s + sub;
#pragma unroll 16
      for (int i = 0; i < 32; ++i) {
        uint32_t mw = mp[(size_t)(i << 11)];       // e2 = p + 8i  (stride 8*256 u32)
        uint32_t hw = hx[256 + p + (i << 3)];
        sc = fmaf(blo(mw), blo(hw), sc);
        sc = fmaf(bhi(mw), bhi(hw), sc);
      }
      sc += __shfl_xor(sc, 32);
      if (lane < 32) red[wv * 32 + lane] = sc;
    }
    __syncthreads();
    if (tid < 32) {
      float sc = red[tid] + red[32 + tid] + red[64 + tid] + red[96 + tid];
      sgl[(b << 8) + 32 * s + tid] = sc * 0.044194173824159216f;   // scaled score
    }
    gbar(cnt, base + 8);
    // ---- SM: softmax over 256 keys (redundant per WG) ----
    {
      float sv = sgl[(b << 8) + tid];
      float mx = sv;
#pragma unroll
      for (int d = 32; d > 0; d >>= 1) mx = fmaxf(mx, __shfl_xor(mx, d));
      if (lane == 0) r_lds[wv] = mx;
      __syncthreads();
      mx = fmaxf(fmaxf(r_lds[0], r_lds[1]), fmaxf(r_lds[2], r_lds[3]));
      float ev = __expf(sv - mx);
      float sm = ev;
#pragma unroll
      for (int d = 32; d > 0; d >>= 1) sm += __shfl_xor(sm, d);
      if (lane == 0) r_lds[4 + wv] = sm;
      __syncthreads();
      float tot = (r_lds[4] + r_lds[5]) + (r_lds[6] + r_lds[7]);
      s_lds[tid] = ev / tot;
    }
    __syncthreads();
    // ---- C: partial ctx for e2 = 32s + sub, k-range p+8i ----
    {
      float cx = 0.f, cy = 0.f;
      const uint32_t* mp = mKb + ((size_t)p << 8) + 32 * s + sub;
#pragma unroll 16
      for (int i = 0; i < 32; ++i) {
        uint32_t mw = mp[(size_t)(i << 11)];       // k = p + 8i
        float av = s_lds[p + (i << 3)];
        cx = fmaf(blo(mw), av, cx);
        cy = fmaf(bhi(mw), av, cy);
      }
      cx += __shfl_xor(cx, 32);
      cy += __shfl_xor(cy, 32);
      if (lane < 32) { red[128 + wv * 32 + lane] = cx; red[256 + wv * 32 + lane] = cy; }
    }
    __syncthreads();
    if (tid < 32) {
      float cx = red[128 + tid] + red[160 + tid] + red[192 + tid] + red[224 + tid];
      float cy = red[256 + tid] + red[288 + tid] + red[320 + tid] + red[352 + tid];
      ctxg[(b << 8) + 32 * s + tid] = bfpack(cx, cy);
    }
    gbar(cnt, base + 16);
    // ---- D: load full ctx; gate row j = (tid&3)*512 + s*64 + (tid>>2) ----
    hx[tid] = ctxg[(b << 8) + tid];
    __syncthreads();
    float acc = bf2f(Xgp[((size_t)b * TT + t) * 2048 + (s << 8) + tid]);
#pragma unroll 8
    for (int kc = 0; kc < 128; ++kc) {
      u32x4 w4 = *(const u32x4*)(wp + kc * 1024);
      u32x4 x4 = *(const u32x4*)(hx + kc * 4);     // broadcast
      acc = fmaf(blo(w4.x), blo(x4.x), acc); acc = fmaf(bhi(w4.x), bhi(x4.x), acc);
      acc = fmaf(blo(w4.y), blo(x4.y), acc); acc = fmaf(bhi(w4.y), bhi(x4.y), acc);
      acc = fmaf(blo(w4.z), blo(x4.z), acc); acc = fmaf(bhi(w4.z), bhi(x4.z), acc);
      acc = fmaf(blo(w4.w), blo(x4.w), acc); acc = fmaf(bhi(w4.w), bhi(x4.w), acc);
    }
    // ---- E: LSTM pointwise; quad lanes hold (i,f,g,o) of state r = s*64 + tid/4 ----
    {
      int lbase = lane & ~3;
      float gi = __shfl(acc, lbase, 64);
      float gf = __shfl(acc, lbase + 1, 64);
      float gg = __shfl(acc, lbase + 2, 64);
      float go = __shfl(acc, lbase + 3, 64);
      c = (1.f / (1.f + __expf(-gf))) * c + (1.f / (1.f + __expf(-gi))) * tanhf(gg);
      float hn = (1.f / (1.f + __expf(-go))) * tanhf(c);
      if ((tid & 3) == 0) {
        int r = (s << 6) + (tid >> 2);
        uint16_t hb = f2bf(hn);
        hgl[(b << 9) + r] = hb;
        hA[((size_t)b * TT + t) * 512 + r] = hb;
      }
    }
    gbar(cnt, base + 24);
    // ---- F: reload full h ----
    hx[256 + tid] = ((const uint32_t*)hgl)[(b << 8) + tid];
    __syncthreads();
  }
}

// ---------------- launch ----------------
extern "C" void kernel_launch(void* const* d_in, const int* in_sizes, int n_in,
                              void* d_out, int out_size, void* d_ws, size_t ws_size,
                              hipStream_t stream) {
  const float* memory = (const float*)d_in[0];
  const int*   tgt    = (const int*)d_in[1];
  const float* emb_in = (const float*)d_in[2];
  const float* W_ih   = (const float*)d_in[3];
  const float* W_hh   = (const float*)d_in[4];
  const float* b_ih   = (const float*)d_in[5];
  const float* b_hh   = (const float*)d_in[6];
  const float* W_out  = (const float*)d_in[7];
  const float* b_out  = (const float*)d_in[8];
  float* out = (float*)d_out;
  char* ws = (char*)d_ws;

  uint32_t* memK  = (uint32_t*)(ws);                    // 8,388,608  [b][k][e2] bf16x2
  uint32_t* memT  = (uint32_t*)(ws + 8388608);          // 8,388,608  [b][e2][k] bf16x2
  uint32_t* Wsl   = (uint32_t*)(ws + 16777216);         // 4,194,304  slice-tiled gate weights
  uint16_t* Wxp   = (uint16_t*)(ws + 20971520);         // 2,097,152  [j][512] bf16
  float*    biasp = (float*)(ws + 23068672);            // 8,192
  uint16_t* WoP   = (uint16_t*)(ws + 23076864);         // 10,354,688 [10112][512] bf16
  uint16_t* Axg   = (uint16_t*)(ws + 33431552);         // 4,194,304  [m][512] bf16
  uint16_t* Xgp   = (uint16_t*)(ws + 37625856);         // 16,777,216 [m][2048] bf16 slice-permuted
  uint16_t* hA    = (uint16_t*)(ws + 54403072);         // 4,194,304  [m][512] bf16
  uint16_t* hgl   = (uint16_t*)(ws + 58597376);         // 32,768     [b][512] bf16 h-exchange
  float*    sgl   = (float*)(ws + 58630144);            // 32,768     [b][256] f32 scores
  uint32_t* ctxg  = (uint32_t*)(ws + 58662912);         // 32,768     [b][256] bf16x2 ctx
  int*      bar   = (int*)(ws + 58695680);              // 4,096      per-batch counters

  hipMemsetAsync(bar, 0, 4096, stream);

  k_prep_mem<<<16384, 256, 0, stream>>>(memory, memK, memT);
  k_prep_wsl<<<4096, 256, 0, stream>>>(W_ih, W_hh, Wsl);
  k_prep_wx<<<4096, 256, 0, stream>>>(W_ih, b_ih, b_hh, Wxp, biasp);
  k_prep_wo<<<20224, 256, 0, stream>>>(W_out, WoP);
  k_gather_x<<<8192, 256, 0, stream>>>(emb_in, tgt, Axg);

  gemm_bt<1><<<32 * 16, 256, 0, stream>>>(Axg, Wxp, biasp, Xgp, 512, 2048, 2048, 16);

  // split-phase per-batch recurrence, XCD-local weight slices
  recur_kernel<<<256, 256, 0, stream>>>(memK, memT, Wsl, Xgp, sgl, ctxg, hgl, hA, bar);

  gemm_bt<0><<<32 * 79, 256, 0, stream>>>(hA, WoP, b_out, out, 512, 10000, 10000, 79);
}

// Round 7
// 3620.182 us; speedup vs baseline: 2.9373x; 2.9373x over previous
//
#include <hip/hip_runtime.h>
#include <stdint.h>

#define TT 128

typedef __attribute__((ext_vector_type(8))) short short8;
typedef __attribute__((ext_vector_type(4))) float f32x4;
typedef __attribute__((ext_vector_type(4))) uint32_t u32x4;

__device__ __forceinline__ float blo(uint32_t u){ union{uint32_t i; float f;} v; v.i = u << 16; return v.f; }
__device__ __forceinline__ float bhi(uint32_t u){ union{uint32_t i; float f;} v; v.i = u & 0xffff0000u; return v.f; }
__device__ __forceinline__ float bf2f(uint16_t u){ union{uint32_t i; float f;} v; v.i = ((uint32_t)u) << 16; return v.f; }
__device__ __forceinline__ uint16_t f2bf(float f){
  union{float f; uint32_t i;} v; v.f = f;
  uint32_t r = v.i + 0x7fffu + ((v.i >> 16) & 1u);
  return (uint16_t)(r >> 16);
}
__device__ __forceinline__ uint32_t bfpack(float a, float b) {
  return (uint32_t)f2bf(a) | ((uint32_t)f2bf(b) << 16);
}
// cache-bypassing exchange ops (agent scope, relaxed — NO cache-wide fences)
__device__ __forceinline__ void xstore(uint32_t* p, uint32_t v) {
  __hip_atomic_store(p, v, __ATOMIC_RELAXED, __HIP_MEMORY_SCOPE_AGENT);
}
__device__ __forceinline__ uint32_t xload(const uint32_t* p) {
  return __hip_atomic_load(p, __ATOMIC_RELAXED, __HIP_MEMORY_SCOPE_AGENT);
}

// ---------------- prep kernels (unchanged from R6) ----------------
__global__ __launch_bounds__(256) void k_prep_mem(const float* __restrict__ mem,
                                                  uint32_t* __restrict__ memK,
                                                  uint32_t* __restrict__ memT) {
  int idx = blockIdx.x * 256 + threadIdx.x;   // 2 * 32*256*256
  if (idx < 2097152) {
    int e2 = idx & 255, k = (idx >> 8) & 255, b = idx >> 16;
    const float* p = mem + ((size_t)(b * 256 + k)) * 512 + e2 * 2;
    memK[idx] = bfpack(p[0], p[1]);
  } else {
    int j = idx - 2097152;
    int k = j & 255, e2 = (j >> 8) & 255, b = j >> 16;
    const float* p = mem + ((size_t)(b * 256 + k)) * 512 + e2 * 2;
    memT[j] = bfpack(p[0], p[1]);
  }
}

// Slice-tiled gate weights: Wsl[s][kc][t][kk], row j = (t&3)*512 + s*64 + (t>>2), k0 = kc*8+kk*2.
__global__ __launch_bounds__(256) void k_prep_wsl(const float* __restrict__ W_ih, const float* __restrict__ W_hh,
                                                  uint32_t* __restrict__ Wsl) {
  int idx = blockIdx.x * 256 + threadIdx.x;   // 1048576
  int kk = idx & 3, t = (idx >> 2) & 255, kc = (idx >> 10) & 127, s = idx >> 17;
  int j = (t & 3) * 512 + s * 64 + (t >> 2);
  int k0 = kc * 8 + kk * 2;
  float w0 = (k0 < 512) ? W_ih[(size_t)j * 1024 + k0] : W_hh[(size_t)j * 512 + (k0 - 512)];
  float w1 = (k0 + 1 < 512) ? W_ih[(size_t)j * 1024 + k0 + 1] : W_hh[(size_t)j * 512 + (k0 + 1 - 512)];
  Wsl[idx] = bfpack(w0, w1);
}

__global__ __launch_bounds__(256) void k_prep_wx(const float* __restrict__ W_ih,
                                                 const float* __restrict__ b_ih, const float* __restrict__ b_hh,
                                                 uint16_t* __restrict__ Wxp, float* __restrict__ biasp) {
  int idx = blockIdx.x * 256 + threadIdx.x;   // 2048*512
  int k = idx & 511, j = idx >> 9;
  Wxp[idx] = f2bf(W_ih[(size_t)j * 1024 + 512 + k]);
  if (k == 0) biasp[j] = b_ih[j] + b_hh[j];
}

__global__ __launch_bounds__(256) void k_prep_wo(const float* __restrict__ W_out, uint16_t* __restrict__ WoP) {
  int idx = blockIdx.x * 256 + threadIdx.x;   // 10112*512 (pad rows zeroed)
  if (idx < 5120000) WoP[idx] = f2bf(W_out[idx]);
  else WoP[idx] = 0;
}

__global__ __launch_bounds__(256) void k_gather_x(const float* __restrict__ emb, const int* __restrict__ tgt,
                                                  uint16_t* __restrict__ Axg) {
  int idx = blockIdx.x * 256 + threadIdx.x;   // 4096*512
  int k = idx & 511, m = idx >> 9;
  Axg[idx] = f2bf(emb[(size_t)tgt[m] * 512 + k]);
}

// ---------------- bf16 MFMA GEMM (unchanged from R6) ----------------
template<int MODE>
__global__ __launch_bounds__(256) void gemm_bt(const uint16_t* __restrict__ A, const uint16_t* __restrict__ B,
                                               const float* __restrict__ bias, void* __restrict__ Cout,
                                               int K, int Nreal, int ldc, int tilesN) {
  __shared__ __align__(16) uint16_t As[128 * 32];
  __shared__ __align__(16) uint16_t Bs[128 * 32];
  const int tid = threadIdx.x;
  const int wv = tid >> 6, lane = tid & 63;
  const int tm = blockIdx.x / tilesN, tn = blockIdx.x % tilesN;
  const int wr = wv >> 1, wc = wv & 1;

  f32x4 acc[4][4];
#pragma unroll
  for (int m = 0; m < 4; ++m)
#pragma unroll
    for (int n = 0; n < 4; ++n) acc[m][n] = (f32x4){0.f, 0.f, 0.f, 0.f};

  const int frow = lane & 15;
  const int fk = (lane >> 4) << 3;
  const int srow = lane >> 2;
  const int skof = (lane & 3) << 3;

  const uint16_t* Abase = A + (size_t)tm * 128 * K;
  const uint16_t* Bbase = B + (size_t)tn * 128 * K;

  for (int k0 = 0; k0 < K; k0 += 32) {
    __syncthreads();
#pragma unroll
    for (int i = 0; i < 2; ++i) {               // 8 chunks of 16 rows = 128 rows
      const int chunk = wv * 2 + i;
      const int row = chunk * 16 + srow;
      const uint16_t* ga = Abase + (size_t)row * K + k0 + skof;
      const uint16_t* gb = Bbase + (size_t)row * K + k0 + skof;
      __builtin_amdgcn_global_load_lds((const __attribute__((address_space(1))) uint32_t*)(const void*)ga,
                                       (__attribute__((address_space(3))) uint32_t*)(void*)(As + chunk * 512),
                                       16, 0, 0);
      __builtin_amdgcn_global_load_lds((const __attribute__((address_space(1))) uint32_t*)(const void*)gb,
                                       (__attribute__((address_space(3))) uint32_t*)(void*)(Bs + chunk * 512),
                                       16, 0, 0);
    }
    __syncthreads();
    short8 af[4], bfr[4];
#pragma unroll
    for (int m = 0; m < 4; ++m) af[m] = *(const short8*)(As + (wr * 64 + m * 16 + frow) * 32 + fk);
#pragma unroll
    for (int n = 0; n < 4; ++n) bfr[n] = *(const short8*)(Bs + (wc * 64 + n * 16 + frow) * 32 + fk);
#pragma unroll
    for (int m = 0; m < 4; ++m)
#pragma unroll
      for (int n = 0; n < 4; ++n)
        acc[m][n] = __builtin_amdgcn_mfma_f32_16x16x32_bf16(af[m], bfr[n], acc[m][n], 0, 0, 0);
  }

  const int crow = (lane >> 4) << 2;
  const int ccol = lane & 15;
#pragma unroll
  for (int n = 0; n < 4; ++n) {
    const int gcol = tn * 128 + wc * 64 + n * 16 + ccol;
    if (gcol < Nreal) {
      const float bv = bias[gcol];
#pragma unroll
      for (int m = 0; m < 4; ++m) {
#pragma unroll
        for (int j = 0; j < 4; ++j) {
          const int grow = tm * 128 + wr * 64 + m * 16 + crow + j;
          const float v = acc[m][n][j] + bv;
          if (MODE == 0) ((float*)Cout)[(size_t)grow * ldc + gcol] = v;
          else {
            int q = gcol >> 9, r = gcol & 511;
            int pos = ((r >> 6) << 8) + ((r & 63) << 2) + q;
            ((uint16_t*)Cout)[(size_t)grow * ldc + pos] = f2bf(v);
          }
        }
      }
    }
  }
}

// ---------------- per-batch 8-WG barrier — NO fences (exchange ops bypass caches) ----------------
// __syncthreads() before the add drains vmcnt(0), so prior agent-scope stores have reached
// the coherence point; pollers read the counter with bypassing loads.
__device__ __forceinline__ void gbar(int* cnt, int target) {
  __syncthreads();
  if (threadIdx.x == 0) {
    __hip_atomic_fetch_add(cnt, 1, __ATOMIC_RELAXED, __HIP_MEMORY_SCOPE_AGENT);
    while (__hip_atomic_load(cnt, __ATOMIC_RELAXED, __HIP_MEMORY_SCOPE_AGENT) < target)
      __builtin_amdgcn_s_sleep(2);
  }
  __syncthreads();
}

// ---------------- recurrence: 256 WGs, g = b*8 + s (XCD = slice), split A/C/D ----------------
__global__ __launch_bounds__(256, 1) void recur_kernel(
    const uint32_t* __restrict__ memK, const uint32_t* __restrict__ memT,
    const uint32_t* __restrict__ Wsl, const uint16_t* __restrict__ Xgp,
    uint32_t* __restrict__ sgl, uint32_t* __restrict__ ctxg,
    uint32_t* __restrict__ hgl, uint16_t* __restrict__ hA, int* __restrict__ bar) {
  __shared__ __align__(16) uint32_t hx[512];       // [0..256)=ctx pairs, [256..512)=h pairs
  __shared__ float s_lds[256];                     // attention weights
  __shared__ float red[384];                       // reduce scratch
  __shared__ float r_lds[8];

  const int g = blockIdx.x;
  const int b = g >> 3, s = g & 7;                 // XCD = g%8 = s (round-robin heuristic)
  const int tid = threadIdx.x;
  const int lane = tid & 63, wv = tid >> 6;
  const int sub = tid & 31, p = tid >> 5;

  const uint32_t* mTb = memT + ((size_t)b << 16);  // [e2][k]
  const uint32_t* mKb = memK + ((size_t)b << 16);  // [k][e2]
  const uint32_t* wp = Wsl + ((size_t)s << 17) + tid * 4;
  int* cnt = bar + b * 32;

  float c = 0.f;
  hx[tid] = 0u; hx[256 + tid] = 0u;
  __syncthreads();

  for (int t = 0; t < TT; ++t) {
    const int base = 24 * t;
    // ---- A: partial scores for keys k = 32s + sub, e2-range p+8i ----
    {
      float sc = 0.f;
      const uint32_t* mp = mTb + ((size_t)p << 8) + 32 * s + sub;
#pragma unroll 16
      for (int i = 0; i < 32; ++i) {
        uint32_t mw = mp[(size_t)(i << 11)];       // e2 = p + 8i
        uint32_t hw = hx[256 + p + (i << 3)];
        sc = fmaf(blo(mw), blo(hw), sc);
        sc = fmaf(bhi(mw), bhi(hw), sc);
      }
      sc += __shfl_xor(sc, 32);
      if (lane < 32) red[wv * 32 + lane] = sc;
    }
    __syncthreads();
    if (tid < 32) {
      float sc = red[tid] + red[32 + tid] + red[64 + tid] + red[96 + tid];
      xstore(&sgl[(b << 8) + 32 * s + tid],
             __builtin_bit_cast(uint32_t, sc * 0.044194173824159216f));
    }
    gbar(cnt, base + 8);
    // ---- SM: softmax over 256 keys (redundant per WG; bypassing reads) ----
    {
      float sv = __builtin_bit_cast(float, xload(&sgl[(b << 8) + tid]));
      float mx = sv;
#pragma unroll
      for (int d = 32; d > 0; d >>= 1) mx = fmaxf(mx, __shfl_xor(mx, d));
      if (lane == 0) r_lds[wv] = mx;
      __syncthreads();
      mx = fmaxf(fmaxf(r_lds[0], r_lds[1]), fmaxf(r_lds[2], r_lds[3]));
      float ev = __expf(sv - mx);
      float sm = ev;
#pragma unroll
      for (int d = 32; d > 0; d >>= 1) sm += __shfl_xor(sm, d);
      if (lane == 0) r_lds[4 + wv] = sm;
      __syncthreads();
      float tot = (r_lds[4] + r_lds[5]) + (r_lds[6] + r_lds[7]);
      s_lds[tid] = ev / tot;
    }
    __syncthreads();
    // ---- C: partial ctx for e2 = 32s + sub, k-range p+8i ----
    {
      float cx = 0.f, cy = 0.f;
      const uint32_t* mp = mKb + ((size_t)p << 8) + 32 * s + sub;
#pragma unroll 16
      for (int i = 0; i < 32; ++i) {
        uint32_t mw = mp[(size_t)(i << 11)];       // k = p + 8i
        float av = s_lds[p + (i << 3)];
        cx = fmaf(blo(mw), av, cx);
        cy = fmaf(bhi(mw), av, cy);
      }
      cx += __shfl_xor(cx, 32);
      cy += __shfl_xor(cy, 32);
      if (lane < 32) { red[128 + wv * 32 + lane] = cx; red[256 + wv * 32 + lane] = cy; }
    }
    __syncthreads();
    if (tid < 32) {
      float cx = red[128 + tid] + red[160 + tid] + red[192 + tid] + red[224 + tid];
      float cy = red[256 + tid] + red[288 + tid] + red[320 + tid] + red[352 + tid];
      xstore(&ctxg[(b << 8) + 32 * s + tid], bfpack(cx, cy));
    }
    gbar(cnt, base + 16);
    // ---- D: load full ctx (bypass); gate row j = (tid&3)*512 + s*64 + (tid>>2) ----
    hx[tid] = xload(&ctxg[(b << 8) + tid]);
    __syncthreads();
    float acc = bf2f(Xgp[((size_t)b * TT + t) * 2048 + (s << 8) + tid]);
#pragma unroll 8
    for (int kc = 0; kc < 128; ++kc) {
      u32x4 w4 = *(const u32x4*)(wp + kc * 1024);
      u32x4 x4 = *(const u32x4*)(hx + kc * 4);     // broadcast
      acc = fmaf(blo(w4.x), blo(x4.x), acc); acc = fmaf(bhi(w4.x), bhi(x4.x), acc);
      acc = fmaf(blo(w4.y), blo(x4.y), acc); acc = fmaf(bhi(w4.y), bhi(x4.y), acc);
      acc = fmaf(blo(w4.z), blo(x4.z), acc); acc = fmaf(bhi(w4.z), bhi(x4.z), acc);
      acc = fmaf(blo(w4.w), blo(x4.w), acc); acc = fmaf(bhi(w4.w), bhi(x4.w), acc);
    }
    // ---- E: LSTM pointwise; quad lanes hold (i,f,g,o) of state r = s*64 + tid/4 ----
    {
      int lbase = lane & ~3;
      float gi = __shfl(acc, lbase, 64);
      float gf = __shfl(acc, lbase + 1, 64);
      float gg = __shfl(acc, lbase + 2, 64);
      float go = __shfl(acc, lbase + 3, 64);
      c = (1.f / (1.f + __expf(-gf))) * c + (1.f / (1.f + __expf(-gi))) * tanhf(gg);
      float hn = (1.f / (1.f + __expf(-go))) * tanhf(c);
      float hn4 = __shfl(hn, (lane & ~7) + 4, 64);       // partner quad's h (state r+1)
      if ((tid & 7) == 0) {
        uint32_t hp = bfpack(hn, hn4);
        int r2 = (s << 5) + (tid >> 3);                  // pair index r/2
        xstore(&hgl[(b << 8) + r2], hp);
        ((uint32_t*)hA)[((size_t)b * TT + t) * 256 + r2] = hp;
      }
    }
    gbar(cnt, base + 24);
    // ---- F: reload full h (bypass) ----
    hx[256 + tid] = xload(&hgl[(b << 8) + tid]);
    __syncthreads();
  }
}

// ---------------- launch ----------------
extern "C" void kernel_launch(void* const* d_in, const int* in_sizes, int n_in,
                              void* d_out, int out_size, void* d_ws, size_t ws_size,
                              hipStream_t stream) {
  const float* memory = (const float*)d_in[0];
  const int*   tgt    = (const int*)d_in[1];
  const float* emb_in = (const float*)d_in[2];
  const float* W_ih   = (const float*)d_in[3];
  const float* W_hh   = (const float*)d_in[4];
  const float* b_ih   = (const float*)d_in[5];
  const float* b_hh   = (const float*)d_in[6];
  const float* W_out  = (const float*)d_in[7];
  const float* b_out  = (const float*)d_in[8];
  float* out = (float*)d_out;
  char* ws = (char*)d_ws;

  uint32_t* memK  = (uint32_t*)(ws);                    // 8,388,608  [b][k][e2] bf16x2
  uint32_t* memT  = (uint32_t*)(ws + 8388608);          // 8,388,608  [b][e2][k] bf16x2
  uint32_t* Wsl   = (uint32_t*)(ws + 16777216);         // 4,194,304  slice-tiled gate weights
  uint16_t* Wxp   = (uint16_t*)(ws + 20971520);         // 2,097,152  [j][512] bf16
  float*    biasp = (float*)(ws + 23068672);            // 8,192
  uint16_t* WoP   = (uint16_t*)(ws + 23076864);         // 10,354,688 [10112][512] bf16
  uint16_t* Axg   = (uint16_t*)(ws + 33431552);         // 4,194,304  [m][512] bf16
  uint16_t* Xgp   = (uint16_t*)(ws + 37625856);         // 16,777,216 [m][2048] bf16 slice-permuted
  uint16_t* hA    = (uint16_t*)(ws + 54403072);         // 4,194,304  [m][512] bf16
  uint32_t* hgl   = (uint32_t*)(ws + 58597376);         // 32,768     [b][256] bf16x2 h-exchange
  uint32_t* sgl   = (uint32_t*)(ws + 58630144);         // 32,768     [b][256] f32 scores
  uint32_t* ctxg  = (uint32_t*)(ws + 58662912);         // 32,768     [b][256] bf16x2 ctx
  int*      bar   = (int*)(ws + 58695680);              // 4,096      per-batch counters

  hipMemsetAsync(bar, 0, 4096, stream);

  k_prep_mem<<<16384, 256, 0, stream>>>(memory, memK, memT);
  k_prep_wsl<<<4096, 256, 0, stream>>>(W_ih, W_hh, Wsl);
  k_prep_wx<<<4096, 256, 0, stream>>>(W_ih, b_ih, b_hh, Wxp, biasp);
  k_prep_wo<<<20224, 256, 0, stream>>>(W_out, WoP);
  k_gather_x<<<8192, 256, 0, stream>>>(emb_in, tgt, Axg);

  gemm_bt<1><<<32 * 16, 256, 0, stream>>>(Axg, Wxp, biasp, Xgp, 512, 2048, 2048, 16);

  // split-phase per-batch recurrence, fence-free barriers + cache-bypass exchange
  recur_kernel<<<256, 256, 0, stream>>>(memK, memT, Wsl, Xgp, sgl, ctxg, hgl, hA, bar);

  gemm_bt<0><<<32 * 79, 256, 0, stream>>>(hA, WoP, b_out, out, 512, 10000, 10000, 79);
}